// Round 2
// baseline (972.223 us; speedup 1.0000x reference)
//
#include <hip/hip_runtime.h>
#include <math.h>

// VQ-VAE forward on MI355X.
// z: (16,256,64,64) f32 ; emb: (1024,256) f32
// Outputs flat f32: z_q(16.7M) | loss | perp | one_hot(67.1M) | idx(65536) | d(67.1M)
// idx must match numpy's FLOAT32 argmin incl. quantization ties at |d|~256 (ulp 1.5-3e-5):
// argmin over q_j = fl32(fl32(znorm+enorm_j) - 2*dot_j), first-index tie-break,
// dot = sequential f32 fmaf chain over k (mimics BLAS microkernel accumulation).

static const size_t O_LOSS = 16777216;
static const size_t O_PERP = 16777217;
static const size_t O_OH   = 16777218;
static const size_t O_IDX  = 83886082;
static const size_t O_D    = 83951618;   // byte offset 8 mod 16 -> float2 stores only

// ws: [0,4096) enormf f32 | [4096,266240) idx i32 | [266240,270336) hist i32 | [270336,278528) loss f64

__global__ __launch_bounds__(256) void vq_enorm(const float* __restrict__ emb,
                                                float* __restrict__ enormf) {
  const int j = blockIdx.x * 256 + threadIdx.x;
  const float* e = emb + ((size_t)j << 8);
  double s = 0.0;
  for (int k = 0; k < 256; ++k) { const double v = (double)e[k]; s += v * v; }
  enormf[j] = (float)s;   // f64-accurate, rounded once (within ~ulp of np's pairwise f32)
}

// 64 rows x 1024 codes per block; 256 threads = (tm=t>>4 rows-group) x (tj=t&15 cols-group),
// 4x4 micro-tile. Single f32 accumulator per cell, strictly ascending k.
__global__ __launch_bounds__(256) void vq_dist(const float* __restrict__ z,
    const float* __restrict__ emb, const float* __restrict__ enormf,
    float* __restrict__ dmat, int* __restrict__ idxw) {
  __shared__ float As[256][68];   // [k][m], 16B-aligned rows (68*4=272B)
  __shared__ float Bs[32][68];    // [k][j] chunk; doubles as znorm-partial scratch
  __shared__ float znf[64];

  const int t = threadIdx.x;
  const int lane = t & 63;
  const int quad = t >> 6;
  const int blk = blockIdx.x;
  const int base = blk << 6;
  const float* zb = z + (((size_t)(blk >> 6)) << 20) + (((size_t)(blk & 63)) << 6);

  // Stage A: full 256x64 tile, float4 loads (16 k-rows x 64 floats per sweep)
  {
    const int kr = t >> 4;
    const int xc = (t & 15) << 2;
    for (int k0 = 0; k0 < 256; k0 += 16) {
      const int k = k0 + kr;
      const float4 v = *(const float4*)&zb[((size_t)k << 12) + xc];
      *(float4*)&As[k][xc] = v;
    }
  }
  __syncthreads();
  // znorm (f64 accurate, rounded once to f32; row-constant shift vs np is order-preserving)
  {
    double* znp = (double*)&Bs[0][0];
    double s = 0.0;
    const int kb = quad << 6;
    for (int k = 0; k < 64; ++k) { const double v = (double)As[kb + k][lane]; s += v * v; }
    znp[(lane << 2) + quad] = s;
    __syncthreads();
    if (t < 64) {
      const double* zp = znp + (t << 2);
      znf[t] = (float)(zp[0] + zp[1] + zp[2] + zp[3]);
    }
  }

  const int tj = t & 15;
  const int tm = t >> 4;
  float m1[4]; int i1[4];
#pragma unroll
  for (int mm = 0; mm < 4; ++mm) { m1[mm] = 3.0e38f; i1[mm] = 0; }

  for (int jt = 0; jt < 16; ++jt) {
    const int j0 = jt << 6;
    float acc[4][4];
#pragma unroll
    for (int a = 0; a < 4; ++a)
#pragma unroll
      for (int q = 0; q < 4; ++q) acc[a][q] = 0.0f;

    for (int kc = 0; kc < 256; kc += 32) {
      __syncthreads();   // also guards Bs overlay reuse on first pass
#pragma unroll
      for (int i = 0; i < 8; ++i) {
        const int jl = (i << 3) + (t >> 5);
        const int kl = t & 31;
        Bs[kl][jl] = emb[(((size_t)(j0 + jl)) << 8) + kc + kl];
      }
      __syncthreads();
#pragma unroll
      for (int k2 = 0; k2 < 32; ++k2) {
        const float4 av = *(const float4*)&As[kc + k2][tm << 2];
        const float4 bv = *(const float4*)&Bs[k2][tj << 2];
        acc[0][0] = fmaf(av.x, bv.x, acc[0][0]);
        acc[0][1] = fmaf(av.x, bv.y, acc[0][1]);
        acc[0][2] = fmaf(av.x, bv.z, acc[0][2]);
        acc[0][3] = fmaf(av.x, bv.w, acc[0][3]);
        acc[1][0] = fmaf(av.y, bv.x, acc[1][0]);
        acc[1][1] = fmaf(av.y, bv.y, acc[1][1]);
        acc[1][2] = fmaf(av.y, bv.z, acc[1][2]);
        acc[1][3] = fmaf(av.y, bv.w, acc[1][3]);
        acc[2][0] = fmaf(av.z, bv.x, acc[2][0]);
        acc[2][1] = fmaf(av.z, bv.y, acc[2][1]);
        acc[2][2] = fmaf(av.z, bv.z, acc[2][2]);
        acc[2][3] = fmaf(av.z, bv.w, acc[2][3]);
        acc[3][0] = fmaf(av.w, bv.x, acc[3][0]);
        acc[3][1] = fmaf(av.w, bv.y, acc[3][1]);
        acc[3][2] = fmaf(av.w, bv.z, acc[3][2]);
        acc[3][3] = fmaf(av.w, bv.w, acc[3][3]);
      }
    }
    // emit: q = fl32(fl32(znorm+enorm_j) - 2*dot)  [x2 exact -> fma-contraction safe]
    float ej[4];
#pragma unroll
    for (int q = 0; q < 4; ++q) ej[q] = enormf[j0 + (tj << 2) + q];
#pragma unroll
    for (int mm = 0; mm < 4; ++mm) {
      const int row = (tm << 2) + mm;
      const float zr = znf[row];
      float qv[4];
#pragma unroll
      for (int q = 0; q < 4; ++q) {
        const float S = zr + ej[q];
        qv[q] = S - 2.0f * acc[mm][q];
      }
      float2* dst = (float2*)&dmat[((size_t)(base + row) << 10) + j0 + (tj << 2)];
      dst[0] = make_float2(qv[0], qv[1]);
      dst[1] = make_float2(qv[2], qv[3]);
#pragma unroll
      for (int q = 0; q < 4; ++q) {
        const float v = qv[q];          // j ascending within lane -> strict < keeps first
        if (v < m1[mm]) { m1[mm] = v; i1[mm] = j0 + (tj << 2) + q; }
      }
    }
  }
  // min+index merge across the 16 tj lanes; lowest-index wins ties (np.argmin rule)
#pragma unroll
  for (int mm = 0; mm < 4; ++mm) {
    float a1 = m1[mm]; int ai = i1[mm];
    for (int off = 8; off >= 1; off >>= 1) {
      const float o1 = __shfl_xor(a1, off, 16);
      const int   oi = __shfl_xor(ai, off, 16);
      if (o1 < a1 || (o1 == a1 && oi < ai)) { a1 = o1; ai = oi; }
    }
    if (tj == 0) idxw[base + (tm << 2) + mm] = ai;
  }
}

// z_q gather + loss partial. One block per 64-row strip; emb rows staged in LDS.
__global__ __launch_bounds__(256) void vq_zq(const float* __restrict__ z,
    const float* __restrict__ emb, const int* __restrict__ idxw,
    float* __restrict__ zq, double* __restrict__ loss_part) {
  __shared__ float E[64][258];
  __shared__ int il[64];
  __shared__ double red[256];
  const int t = threadIdx.x;
  const int blk = blockIdx.x;
  const int base = blk << 6;
  if (t < 64) il[t] = idxw[base + t];
  __syncthreads();
  for (int i = 0; i < 64; ++i) E[i][t] = emb[((size_t)il[i] << 8) + t];
  __syncthreads();
  const int w = t & 63, cg = t >> 6;
  const size_t zbase = (((size_t)(blk >> 6)) << 20) + (((size_t)(blk & 63)) << 6) + (size_t)w;
  double ls = 0.0;
  for (int ci = 0; ci < 64; ++ci) {
    const int c = (ci << 2) + cg;
    const float e = E[w][c];
    const size_t o = zbase + ((size_t)c << 12);
    const float zv = z[o];
    zq[o] = e;
    const double dd = (double)e - (double)zv;
    ls += dd * dd;
  }
  red[t] = ls;
  __syncthreads();
  for (int off = 128; off > 0; off >>= 1) {
    if (t < off) red[t] += red[t + off];
    __syncthreads();
  }
  if (t == 0) loss_part[blk] = red[0];
}

__global__ __launch_bounds__(256) void vq_scatter(const int* __restrict__ idxw,
    float* __restrict__ out, int* __restrict__ hist) {
  const int m = blockIdx.x * 256 + threadIdx.x;
  const int idx = idxw[m];
  out[O_OH + ((size_t)m << 10) + (size_t)idx] = 1.0f;
  out[O_IDX + (size_t)m] = (float)idx;
  atomicAdd(&hist[idx], 1);
}

__global__ __launch_bounds__(256) void vq_final(const double* __restrict__ loss_part,
    const int* __restrict__ hist, float* __restrict__ out) {
  __shared__ double red[256];
  const int t = threadIdx.x;
  double s = 0.0;
  for (int i = t; i < 1024; i += 256) s += loss_part[i];
  red[t] = s;
  __syncthreads();
  for (int off = 128; off > 0; off >>= 1) {
    if (t < off) red[t] += red[t + off];
    __syncthreads();
  }
  if (t == 0) out[O_LOSS] = (float)(1.25 * red[0] / 16777216.0);
  __syncthreads();
  double h = 0.0;
  for (int i = t; i < 1024; i += 256) {
    const double p = (double)hist[i] / 65536.0;
    h += p * log(p + 1e-10);
  }
  red[t] = h;
  __syncthreads();
  for (int off = 128; off > 0; off >>= 1) {
    if (t < off) red[t] += red[t + off];
    __syncthreads();
  }
  if (t == 0) out[O_PERP] = (float)exp(-red[0]);
}

extern "C" void kernel_launch(void* const* d_in, const int* in_sizes, int n_in,
                              void* d_out, int out_size, void* d_ws, size_t ws_size,
                              hipStream_t stream) {
  const float* z   = (const float*)d_in[0];
  const float* emb = (const float*)d_in[1];
  float* out = (float*)d_out;

  float* enormf    = (float*)d_ws;
  int* idxw        = (int*)((char*)d_ws + 4096);
  int* hist        = (int*)((char*)d_ws + 266240);
  double* loss_part= (double*)((char*)d_ws + 270336);

  vq_enorm<<<4, 256, 0, stream>>>(emb, enormf);
  hipMemsetAsync((char*)d_ws + 266240, 0, 4096, stream);                 // hist
  hipMemsetAsync((char*)d_out + O_OH * sizeof(float), 0,
                 (size_t)67108864 * sizeof(float), stream);              // one_hot zeros
  vq_dist<<<1024, 256, 0, stream>>>(z, emb, enormf, out + O_D, idxw);
  vq_zq<<<1024, 256, 0, stream>>>(z, emb, idxw, out, loss_part);
  vq_scatter<<<256, 256, 0, stream>>>(idxw, out, hist);
  vq_final<<<1, 256, 0, stream>>>(loss_part, hist, out);
}